// Round 3
// baseline (192.377 us; speedup 1.0000x reference)
//
#include <hip/hip_runtime.h>

// x: [128][256][256][3] fp32, C: [768][4][256][4] fp32 -> [3072][1024]
// out[b,kl,hw] = S_x[b,hw] * S_C[kl]  (einsum factorizes; no shared labels)
//
// Pipeline:
//   A: psC[96][1024]  - partial column sums of C (32 rows per block)
//   B1: rowsum[b][h][768] - sum of the 32 image rows with y%8==h (pure streaming,
//       no LDS, no barrier, 1 float4 accumulator/thread)
//   B2: finalize sx[b][64] (bin rowsum by w,c) and sC[1024] (fold psC)
//   C: out = sx outer sC
//
// ws layout (floats), every element overwritten each call (no zeroing needed):
//   rowsum[128*8*768] | psC[96*1024] | sC[1024] | sx[128*64]

#define ROWSUM_ELEMS (128 * 8 * 768)
#define PSC_ELEMS    (96 * 1024)

// ---------- A: C column partial sums ----------
__global__ __launch_bounds__(256) void reduce_C_part(const float* __restrict__ C,
                                                     float4* __restrict__ psC) {
    const int p = blockIdx.x;          // 96 row-groups
    const int t = threadIdx.x;         // 256 float4 cols
    const float4* row = (const float4*)C + (size_t)p * 32 * 256 + t;
    float4 a = {0.f, 0.f, 0.f, 0.f};
#pragma unroll
    for (int r = 0; r < 32; ++r) {
        float4 v = row[(size_t)r * 256];
        a.x += v.x; a.y += v.y; a.z += v.z; a.w += v.w;
    }
    psC[p * 256 + t] = a;
}

// ---------- B1: row-group sum (pure streaming) ----------
// Block blk = b*8+h, 192 threads. Thread t sums float4 column t over the 32
// rows y = h+8j. Each wave-load is 1 KiB contiguous; 32 independent loads,
// one float4 accumulator -> minimal VGPRs, deep pipelining, no LDS/barrier.
__global__ __launch_bounds__(192) void reduce_rows(const float* __restrict__ x,
                                                   float4* __restrict__ rowsum) {
    const int blk = blockIdx.x;                 // [0, 1024)
    const int b = blk >> 3, h = blk & 7;
    const int t = threadIdx.x;                  // [0, 192)
    const float4* xb = (const float4*)x + (size_t)b * 49152 + (size_t)h * 192 + t;
    float4 a = {0.f, 0.f, 0.f, 0.f};
#pragma unroll
    for (int j = 0; j < 32; ++j) {              // stride 8 rows = 1536 float4
        float4 v = xb[(size_t)j * 1536];
        a.x += v.x; a.y += v.y; a.z += v.z; a.w += v.w;
    }
    rowsum[(size_t)blk * 192 + t] = a;
}

// ---------- B2: finalize sx and sC ----------
// blocks 0..127: bin rowsum[b] (8 rows x 768 floats, L2-hot) into sx[b][64]
// blocks 128..135: fold psC columns into sC
__global__ __launch_bounds__(128) void finalize(const float* __restrict__ rowsum,
                                                const float* __restrict__ psC,
                                                float* __restrict__ sx,
                                                float* __restrict__ sC) {
    const int blk = blockIdx.x, t = threadIdx.x;
    if (blk < 128) {
        if (t < 64) {
            const int h = t >> 3, w = t & 7;
            const float* r = rowsum + (size_t)blk * 6144 + h * 768 + 3 * w;
            float s = 0.f;
#pragma unroll
            for (int g = 0; g < 32; ++g)
                s += r[24 * g] + r[24 * g + 1] + r[24 * g + 2];
            sx[blk * 64 + t] = s;
        }
    } else {
        const int col = (blk - 128) * 128 + t;
        float s = 0.f;
#pragma unroll
        for (int p = 0; p < 96; ++p) s += psC[p * 1024 + col];
        sC[col] = s;
    }
}

// ---------- C: outer-product expansion ----------
__global__ __launch_bounds__(256) void expand_kernel(const float* __restrict__ sx,
                                                     const float* __restrict__ sC,
                                                     float4* __restrict__ out) {
    const int b = blockIdx.y, bx = blockIdx.x, t = threadIdx.x;
    __shared__ float sxl[64];
    __shared__ float sCl[64];
    if (t < 64)       sxl[t]      = sx[b * 64 + t];
    else if (t < 128) sCl[t - 64] = sC[bx * 64 + (t - 64)];
    __syncthreads();

    const float4 v = ((const float4*)sxl)[t & 15];
    float4* ob = out + (size_t)b * 16384 + bx * 1024 + t;
#pragma unroll
    for (int u = 0; u < 4; ++u) {
        const float s = sCl[(t >> 4) + 16 * u];
        float4 rr; rr.x = v.x * s; rr.y = v.y * s; rr.z = v.z * s; rr.w = v.w * s;
        ob[256 * u] = rr;
    }
}

extern "C" void kernel_launch(void* const* d_in, const int* in_sizes, int n_in,
                              void* d_out, int out_size, void* d_ws, size_t ws_size,
                              hipStream_t stream) {
    const float* x = (const float*)d_in[0];
    const float* C = (const float*)d_in[1];
    float* out = (float*)d_out;

    float* rowsum = (float*)d_ws;
    float* psC    = rowsum + ROWSUM_ELEMS;
    float* sC     = psC + PSC_ELEMS;
    float* sx     = sC + 1024;

    reduce_C_part<<<dim3(96),      256, 0, stream>>>(C, (float4*)psC);
    reduce_rows  <<<dim3(1024),    192, 0, stream>>>(x, (float4*)rowsum);
    finalize     <<<dim3(136),     128, 0, stream>>>(rowsum, psC, sx, sC);
    expand_kernel<<<dim3(16, 128), 256, 0, stream>>>(sx, sC, (float4*)out);
}